// Round 5
// baseline (2409.342 us; speedup 1.0000x reference)
//
#include <hip/hip_runtime.h>
#include <hip/hip_bf16.h>

#define BB 8
#define NN 2048
#define MM (BB*NN)
#define KNN 32
#define TI 8

// ---------------------------------------------------------------- dtype detect
// Interpret first 24576 u16 of x as bf16; count insane exponents (|v|>=32 or
// NaN/Inf). Genuine bf16 N(0,1): ~0 hits. fp32-stored: low mantissa halves are
// ~random -> ~25% insane. flag=1 means inputs are fp32.
__global__ void detect_dtype_kernel(const unsigned short* __restrict__ p,
                                    int n16, int* __restrict__ flag) {
    __shared__ int cnt;
    if (threadIdx.x == 0) cnt = 0;
    __syncthreads();
    int local = 0;
    for (int i = threadIdx.x; i < n16; i += 256) {
        int e = (p[i] >> 7) & 0xFF;
        if (e >= 132) local++;     // |v| >= 2^5, or inf/nan
    }
    atomicAdd(&cnt, local);
    __syncthreads();
    if (threadIdx.x == 0) *flag = (cnt > 100) ? 1 : 0;
}

// ---------------------------------------------------------------- diagnostic
__global__ void diag_fill_kernel(__hip_bfloat16* __restrict__ out, int n, float marker) {
    int i = blockIdx.x * 256 + threadIdx.x;
    if (i < n) out[i] = __float2bfloat16(marker);
}

// ---------------------------------------------------------------- utilities
__global__ void upcast_kernel(const void* __restrict__ in, float* __restrict__ out,
                              int n, const int* __restrict__ flag) {
    int f32 = *flag;
    int i = blockIdx.x * 256 + threadIdx.x;
    if (i < n)
        out[i] = f32 ? ((const float*)in)[i]
                     : __bfloat162float(((const __hip_bfloat16*)in)[i]);
}

// W: (2C, Cout) -> Wa = Wtop - Wbot, Wc = Wbot (C x Cout fp32), bf = bias.
// EdgeConv decomposition:
//   max_j act([x_i, x_j - x_i] W + b) = act(x_i Wa + b + max_j (x_j Wc))
__global__ void prep_w_kernel(const void* __restrict__ W, const void* __restrict__ bvec,
                              float* __restrict__ Wa, float* __restrict__ Wc,
                              float* __restrict__ bf, int C, int Cout,
                              const int* __restrict__ flag) {
    int f32 = *flag;
    int total = C * Cout;
    int gid = blockIdx.x * 256 + threadIdx.x;
    for (int t = gid; t < total; t += gridDim.x * 256) {
        int k = t / Cout, n = t % Cout;
        float top, bot;
        if (f32) {
            top = ((const float*)W)[k * Cout + n];
            bot = ((const float*)W)[(C + k) * Cout + n];
        } else {
            top = __bfloat162float(((const __hip_bfloat16*)W)[k * Cout + n]);
            bot = __bfloat162float(((const __hip_bfloat16*)W)[(C + k) * Cout + n]);
        }
        Wa[t] = top - bot;
        Wc[t] = bot;
    }
    if (gid < Cout)
        bf[gid] = f32 ? ((const float*)bvec)[gid]
                      : __bfloat162float(((const __hip_bfloat16*)bvec)[gid]);
}

__global__ void sqnorm_kernel(const float* __restrict__ X, float* __restrict__ sq, int C) {
    int row = blockIdx.x * 256 + threadIdx.x;
    if (row < MM) {
        float s = 0.f;
        for (int c = 0; c < C; c++) { float v = X[(size_t)row * C + c]; s += v * v; }
        sq[row] = s;
    }
}

// X (B,N,C) -> XT (B,C,N)
__global__ void transpose_kernel(const float* __restrict__ X, float* __restrict__ XT, int C) {
    __shared__ float tile[32][33];
    int b = blockIdx.z;
    int n0 = blockIdx.x * 32, c0 = blockIdx.y * 32;
    int tx = threadIdx.x, ty = threadIdx.y;   // 32 x 8
    for (int k = 0; k < 32; k += 8) {
        int n = n0 + ty + k, c = c0 + tx;
        tile[ty + k][tx] = (c < C) ? X[((size_t)b * NN + n) * C + c] : 0.f;
    }
    __syncthreads();
    for (int k = 0; k < 32; k += 8) {
        int c = c0 + ty + k, n = n0 + tx;
        if (c < C) XT[((size_t)b * C + c) * NN + n] = tile[tx][ty + k];
    }
}

// ---------------------------------------------------------------- kNN
__global__ __launch_bounds__(256)
void knn_kernel(const float* __restrict__ X, const float* __restrict__ XT,
                const float* __restrict__ sq, int C, int* __restrict__ idxout) {
    int b = blockIdx.x & 7;                    // XCD swizzle: batch -> XCD
    int i0 = (blockIdx.x >> 3) * TI;
    int tid = threadIdx.x;
    __shared__ float qs[TI][128];
    __shared__ float qsq[TI];
    __shared__ float rv[4];
    __shared__ int   ri[4];

    for (int t = tid; t < TI * C; t += 256) {
        int r = t / C, c = t % C;
        qs[r][c] = X[((size_t)b * NN + i0 + r) * C + c];
    }
    if (tid < TI) qsq[tid] = sq[b * NN + i0 + tid];
    __syncthreads();

    float d[TI][8];
#pragma unroll
    for (int r = 0; r < TI; r++)
#pragma unroll
        for (int p = 0; p < 8; p++) d[r][p] = 0.f;

    const float* xtb = XT + (size_t)b * C * NN;
    for (int c = 0; c < C; c++) {
        float xv[8];
#pragma unroll
        for (int p = 0; p < 8; p++) xv[p] = xtb[(size_t)c * NN + tid + 256 * p];
#pragma unroll
        for (int r = 0; r < TI; r++) {
            float q = qs[r][c];
#pragma unroll
            for (int p = 0; p < 8; p++) d[r][p] += q * xv[p];
        }
    }
#pragma unroll
    for (int p = 0; p < 8; p++) {
        float sj = sq[b * NN + tid + 256 * p];
#pragma unroll
        for (int r = 0; r < TI; r++) d[r][p] = qsq[r] + sj - 2.f * d[r][p];
    }

    int lane = tid & 63, wv_id = tid >> 6;
#pragma unroll
    for (int r = 0; r < TI; r++) {
        float lv = 3.4e38f; int li = 0x7fffffff;
#pragma unroll
        for (int p = 0; p < 8; p++) {
            int j = tid + 256 * p;
            if (d[r][p] < lv) { lv = d[r][p]; li = j; }
        }
        for (int it = 0; it < KNN + 1; it++) {
            float v = lv; int vi = li;
#pragma unroll
            for (int s = 32; s; s >>= 1) {
                float ov = __shfl_xor(v, s);
                int   oi = __shfl_xor(vi, s);
                if (ov < v || (ov == v && oi < vi)) { v = ov; vi = oi; }
            }
            if (lane == 0) { rv[wv_id] = v; ri[wv_id] = vi; }
            __syncthreads();
            float wvv = rv[0]; int wi = ri[0];
#pragma unroll
            for (int w = 1; w < 4; w++) {
                float ov = rv[w]; int oi = ri[w];
                if (ov < wvv || (ov == wvv && oi < wi)) { wvv = ov; wi = oi; }
            }
            __syncthreads();   // rv/ri reused next iteration
            if (li == wi) {    // unique owner of the extracted point
                if (it > 0)
                    idxout[(((size_t)b * NN) + i0 + r) * KNN + (it - 1)] = wi;
                lv = 3.4e38f; li = 0x7fffffff;
#pragma unroll
                for (int pp = 0; pp < 8; pp++) {
                    int j = tid + 256 * pp;
                    if (j == wi) d[r][pp] = 3.4e38f;
                    float dv = d[r][pp];
                    if (dv < lv) { lv = dv; li = j; }
                }
            }
        }
    }
}

// ---------------------------------------------------------------- GEMM
// out = act( [A1|A2](M x K1+K2) @ W(:, slice) + bias + Mx ).
// FINAL=0: fp32 out (col_off ignored must be pre-added by caller).
// FINAL=1: output dtype per *dflag (1=fp32, 0=bf16), NaN scrubbed to 333.0f,
//          store at column col_off+col0 of base pointer out.
template<bool RELU, int FINAL, bool ADDMX, bool HASBIAS>
__global__ __launch_bounds__(256)
void gemm_kernel(const float* __restrict__ A1, int K1,
                 const float* __restrict__ A2, int K2,
                 const float* __restrict__ W, int ldw,
                 const float* __restrict__ bias,
                 const float* __restrict__ Mx, int ldmx,
                 void* __restrict__ out, int ldo, int col_off,
                 const int* __restrict__ dflag) {
    const int Kdim = K1 + K2;
    __shared__ __align__(16) float As[16][68];
    __shared__ __align__(16) float Bs[16][68];
    int f32o = FINAL ? *dflag : 1;
    int tid = threadIdx.x;
    int tx = tid % 16, ty = tid / 16;
    int bm = blockIdx.y * 64, bn = blockIdx.x * 64;
    float acc[4][4] = {};
    for (int k0 = 0; k0 < Kdim; k0 += 16) {
        for (int e = tid; e < 64 * 16; e += 256) {
            int row = e >> 4, col = e & 15;
            int k = k0 + col;
            float v = 0.f;
            if (k < K1)        v = A1[(size_t)(bm + row) * K1 + k];
            else if (k < Kdim) v = A2[(size_t)(bm + row) * K2 + (k - K1)];
            As[col][row] = v;
        }
        for (int e = tid; e < 16 * 64; e += 256) {
            int row = e >> 6, col = e & 63;
            int k = k0 + row;
            Bs[row][col] = (k < Kdim) ? W[(size_t)k * ldw + bn + col] : 0.f;
        }
        __syncthreads();
#pragma unroll
        for (int kk = 0; kk < 16; kk++) {
            float4 av = *(const float4*)&As[kk][ty * 4];
            float4 bv = *(const float4*)&Bs[kk][tx * 4];
            float a[4] = {av.x, av.y, av.z, av.w};
            float bb[4] = {bv.x, bv.y, bv.z, bv.w};
#pragma unroll
            for (int i = 0; i < 4; i++)
#pragma unroll
                for (int j = 0; j < 4; j++) acc[i][j] += a[i] * bb[j];
        }
        __syncthreads();
    }
#pragma unroll
    for (int i = 0; i < 4; i++) {
        int row = bm + ty * 4 + i;
        int col0 = bn + tx * 4;
        float o[4];
#pragma unroll
        for (int j = 0; j < 4; j++) {
            o[j] = acc[i][j];
            if (HASBIAS) o[j] += bias[col0 + j];
            if (ADDMX)   o[j] += Mx[(size_t)row * ldmx + col0 + j];
            if (RELU)    o[j] = fmaxf(o[j], 0.f);
            if (FINAL)   o[j] = (o[j] != o[j]) ? 333.0f : o[j];   // NaN scrub marker
        }
        if (FINAL) {
            if (f32o) {
                float* op = (float*)out + (size_t)row * ldo + col_off + col0;
                float4 ov = {o[0], o[1], o[2], o[3]};
                *(float4*)op = ov;
            } else {
                __hip_bfloat16* op = (__hip_bfloat16*)out + (size_t)row * ldo + col_off + col0;
#pragma unroll
                for (int j = 0; j < 4; j++) op[j] = __float2bfloat16(o[j]);
            }
        } else {
            float4 ov = {o[0], o[1], o[2], o[3]};
            *(float4*)((float*)out + (size_t)row * ldo + col0) = ov;
        }
    }
}

// ---------------------------------------------------------------- gather-max
__global__ void gather_kernel(const float* __restrict__ Cc, const int* __restrict__ idx,
                              float* __restrict__ Mx, int CW) {
    int L = blockIdx.x;
    int b = L & 7;                 // XCD swizzle: batch b -> XCD b (L2 locality)
    int i = L >> 3;
    int row = b * NN + i;
    int ch = threadIdx.x;
    __shared__ int sidx[KNN];
    if (ch < KNN) sidx[ch] = idx[(size_t)row * KNN + ch] & (NN - 1);  // clamp
    __syncthreads();
    const float* cbase = Cc + (size_t)b * NN * CW;
    float m = -3.4e38f;
#pragma unroll 4
    for (int t = 0; t < KNN; t++) {
        int j = sidx[t];
        m = fmaxf(m, cbase[(size_t)j * CW + ch]);
    }
    Mx[(size_t)row * CW + ch] = m;
}

// ---------------------------------------------------------------- launch
extern "C" void kernel_launch(void* const* d_in, const int* in_sizes, int n_in,
                              void* d_out, int out_size, void* d_ws, size_t ws_size,
                              hipStream_t stream) {
    const void* x  = d_in[0];
    const void* W1 = d_in[1];
    const void* b1 = d_in[2];
    const void* W2 = d_in[3];
    const void* b2 = d_in[4];
    const void* W3 = d_in[5];
    const void* b3 = d_in[6];

    const size_t WEIGHTS = (size_t)(3*64*2 + 64) + (64*128*2 + 128) + (192*512*2 + 512);
    const size_t fixed   = (size_t)MM*64 + (size_t)MM*128 + (size_t)MM*32 + WEIGHTS + 16;
    const size_t need64  = (fixed + (size_t)MM*2*64)  * 4;
    const size_t need128 = (fixed + (size_t)MM*2*128) * 4;

    if (d_ws == nullptr || ws_size < need64) {
        float marker = 100.0f + (float)(ws_size >> 20);
        diag_fill_kernel<<<(out_size + 255) / 256, 256, 0, stream>>>(
            (__hip_bfloat16*)d_out, out_size, marker);
        return;
    }
    const int CW = (ws_size >= need128) ? 128 : 64;

    float* ws = (float*)d_ws;
    size_t o = 0;
    float* X1   = ws + o; o += (size_t)MM * 64;
    float* X2   = ws + o; o += (size_t)MM * 128;
    float* Cch  = ws + o; o += (size_t)MM * CW;
    float* Mx   = ws + o; o += (size_t)MM * CW;
    float* Wa1  = ws + o; o += 3 * 64;
    float* Wc1  = ws + o; o += 3 * 64;
    float* bf1  = ws + o; o += 64;
    float* Wa2  = ws + o; o += 64 * 128;
    float* Wc2  = ws + o; o += 64 * 128;
    float* bf2  = ws + o; o += 128;
    float* Wa3  = ws + o; o += 192 * 512;
    float* Wc3  = ws + o; o += 192 * 512;
    float* bf3  = ws + o; o += 512;
    int*   idxb = (int*)(ws + o); o += (size_t)MM * KNN;
    int*   dflag = (int*)(ws + o); o += 16;

    // XT / X0 / SQ live in d_out: dead before any final output write.
    // (d_out >= out_size*2 bytes = 16.7 MB even if bf16; scratch uses 8.65 MB.)
    float* XT = (float*)d_out;                         // MM*128 floats max
    float* X0 = XT + (size_t)MM * 128;                 // MM*3 floats
    float* SQ = X0 + (size_t)MM * 3;                   // MM floats

    // dtype detect + prep
    detect_dtype_kernel<<<1, 256, 0, stream>>>((const unsigned short*)x, 24576, dflag);
    upcast_kernel<<<(MM * 3 + 255) / 256, 256, 0, stream>>>(x, X0, MM * 3, dflag);
    prep_w_kernel<<<1,   256, 0, stream>>>(W1, b1, Wa1, Wc1, bf1, 3, 64, dflag);
    prep_w_kernel<<<32,  256, 0, stream>>>(W2, b2, Wa2, Wc2, bf2, 64, 128, dflag);
    prep_w_kernel<<<384, 256, 0, stream>>>(W3, b3, Wa3, Wc3, bf3, 192, 512, dflag);

    // Chunked EdgeConv tail.
    auto edge_tail = [&](const float* A1, int K1, const float* A2, int K2,
                         const float* Wa, const float* Wc, const float* bfp, int Cout,
                         void* outp, int ldo, bool relu, bool final) {
        for (int n0 = 0; n0 < Cout; ) {
            int w = Cout - n0 < CW ? Cout - n0 : CW;
            dim3 g(w / 64, MM / 64);
            gemm_kernel<false, 0, false, false><<<g, 256, 0, stream>>>(
                A1, K1, A2, K2, Wc + n0, Cout, nullptr, nullptr, 0,
                (void*)Cch, w, 0, dflag);
            gather_kernel<<<MM, w, 0, stream>>>(Cch, idxb, Mx, w);
            if (final) {
                gemm_kernel<false, 1, true, true><<<g, 256, 0, stream>>>(
                    A1, K1, A2, K2, Wa + n0, Cout, bfp + n0, Mx, w,
                    outp, ldo, n0, dflag);
            } else {
                void* op = (void*)((float*)outp + n0);
                if (relu)
                    gemm_kernel<true, 0, true, true><<<g, 256, 0, stream>>>(
                        A1, K1, A2, K2, Wa + n0, Cout, bfp + n0, Mx, w, op, ldo, 0, dflag);
                else
                    gemm_kernel<false, 0, true, true><<<g, 256, 0, stream>>>(
                        A1, K1, A2, K2, Wa + n0, Cout, bfp + n0, Mx, w, op, ldo, 0, dflag);
            }
            n0 += w;
        }
    };

    // ---- stage 1 (C=3 -> 64)
    sqnorm_kernel<<<MM / 256, 256, 0, stream>>>(X0, SQ, 3);
    transpose_kernel<<<dim3(NN / 32, 1, BB), dim3(32, 8), 0, stream>>>(X0, XT, 3);
    knn_kernel<<<MM / TI, 256, 0, stream>>>(X0, XT, SQ, 3, idxb);
    edge_tail(X0, 3, nullptr, 0, Wa1, Wc1, bf1, 64, (void*)X1, 64, true, false);

    // ---- stage 2 (C=64 -> 128)
    sqnorm_kernel<<<MM / 256, 256, 0, stream>>>(X1, SQ, 64);
    transpose_kernel<<<dim3(NN / 32, 2, BB), dim3(32, 8), 0, stream>>>(X1, XT, 64);
    knn_kernel<<<MM / TI, 256, 0, stream>>>(X1, XT, SQ, 64, idxb);
    edge_tail(X1, 64, nullptr, 0, Wa2, Wc2, bf2, 128, (void*)X2, 128, true, false);

    // ---- stage 3 (C=192 = [X1|X2] -> 512, no relu, final out)
    sqnorm_kernel<<<MM / 256, 256, 0, stream>>>(X2, SQ, 128);
    transpose_kernel<<<dim3(NN / 32, 4, BB), dim3(32, 8), 0, stream>>>(X2, XT, 128);
    knn_kernel<<<MM / TI, 256, 0, stream>>>(X2, XT, SQ, 128, idxb);
    edge_tail(X1, 64, X2, 128, Wa3, Wc3, bf3, 512, d_out, 512, false, true);
}

// Round 6
// 1123.638 us; speedup vs baseline: 2.1442x; 2.1442x over previous
//
#include <hip/hip_runtime.h>
#include <hip/hip_bf16.h>

#define BB 8
#define NN 2048
#define MM (BB*NN)
#define KNN 32
#define TI 8

// ---------------------------------------------------------------- dtype detect
// Interpret first 24576 u16 of x as bf16; count insane exponents. fp32-stored
// inputs -> ~25% hits; genuine bf16 N(0,1) -> ~0. flag=1 means fp32 inputs.
__global__ void detect_dtype_kernel(const unsigned short* __restrict__ p,
                                    int n16, int* __restrict__ flag) {
    __shared__ int cnt;
    if (threadIdx.x == 0) cnt = 0;
    __syncthreads();
    int local = 0;
    for (int i = threadIdx.x; i < n16; i += 256) {
        int e = (p[i] >> 7) & 0xFF;
        if (e >= 132) local++;     // |v| >= 2^5, or inf/nan
    }
    atomicAdd(&cnt, local);
    __syncthreads();
    if (threadIdx.x == 0) *flag = (cnt > 100) ? 1 : 0;
}

// ---------------------------------------------------------------- diagnostic
__global__ void diag_fill_kernel(__hip_bfloat16* __restrict__ out, int n, float marker) {
    int i = blockIdx.x * 256 + threadIdx.x;
    if (i < n) out[i] = __float2bfloat16(marker);
}

// ---------------------------------------------------------------- utilities
__global__ void upcast_kernel(const void* __restrict__ in, float* __restrict__ out,
                              int n, const int* __restrict__ flag) {
    int f32 = *flag;
    int i = blockIdx.x * 256 + threadIdx.x;
    if (i < n)
        out[i] = f32 ? ((const float*)in)[i]
                     : __bfloat162float(((const __hip_bfloat16*)in)[i]);
}

// W: (2C, Cout) -> Wa = Wtop - Wbot, Wc = Wbot (C x Cout fp32), bf = bias.
// EdgeConv decomposition:
//   max_j act([x_i, x_j - x_i] W + b) = act(x_i Wa + b + max_j (x_j Wc))
__global__ void prep_w_kernel(const void* __restrict__ W, const void* __restrict__ bvec,
                              float* __restrict__ Wa, float* __restrict__ Wc,
                              float* __restrict__ bf, int C, int Cout,
                              const int* __restrict__ flag) {
    int f32 = *flag;
    int total = C * Cout;
    int gid = blockIdx.x * 256 + threadIdx.x;
    for (int t = gid; t < total; t += gridDim.x * 256) {
        int k = t / Cout, n = t % Cout;
        float top, bot;
        if (f32) {
            top = ((const float*)W)[k * Cout + n];
            bot = ((const float*)W)[(C + k) * Cout + n];
        } else {
            top = __bfloat162float(((const __hip_bfloat16*)W)[k * Cout + n]);
            bot = __bfloat162float(((const __hip_bfloat16*)W)[(C + k) * Cout + n]);
        }
        Wa[t] = top - bot;
        Wc[t] = bot;
    }
    if (gid < Cout)
        bf[gid] = f32 ? ((const float*)bvec)[gid]
                      : __bfloat162float(((const __hip_bfloat16*)bvec)[gid]);
}

__global__ void sqnorm_kernel(const float* __restrict__ X, float* __restrict__ sq, int C) {
    int row = blockIdx.x * 256 + threadIdx.x;
    if (row < MM) {
        float s = 0.f;
        for (int c = 0; c < C; c++) { float v = X[(size_t)row * C + c]; s += v * v; }
        sq[row] = s;
    }
}

// X (B,N,C) -> XT (B,C,N)
__global__ void transpose_kernel(const float* __restrict__ X, float* __restrict__ XT, int C) {
    __shared__ float tile[32][33];
    int b = blockIdx.z;
    int n0 = blockIdx.x * 32, c0 = blockIdx.y * 32;
    int tx = threadIdx.x, ty = threadIdx.y;   // 32 x 8
    for (int k = 0; k < 32; k += 8) {
        int n = n0 + ty + k, c = c0 + tx;
        tile[ty + k][tx] = (c < C) ? X[((size_t)b * NN + n) * C + c] : 0.f;
    }
    __syncthreads();
    for (int k = 0; k < 32; k += 8) {
        int c = c0 + ty + k, n = n0 + tx;
        if (c < C) XT[((size_t)b * C + c) * NN + n] = tile[tx][ty + k];
    }
}

// ---------------------------------------------------------------- kNN
// Distance phase: block computes d[8 rows][2048 pts] register-tiled (XT read
// once per block). Selection phase: distances go to LDS 4 rows at a time;
// each wave owns one full row and extracts 33 mins barrier-free:
// per-lane cached (min,idx) over 32 candidates, 6-step shfl fmin butterfly,
// ballot -> owner, owner clears winner in LDS and rescans its 32.
__global__ __launch_bounds__(256)
void knn_kernel(const float* __restrict__ X, const float* __restrict__ XT,
                const float* __restrict__ sq, int C, int* __restrict__ idxout) {
    int b = blockIdx.x & 7;                    // XCD swizzle: batch -> XCD
    int i0 = (blockIdx.x >> 3) * TI;
    int tid = threadIdx.x;
    __shared__ float qs[TI][128];
    __shared__ float qsq[TI];
    __shared__ __align__(16) float dl[4][NN];  // 32 KB: 4 rows per pass

    for (int t = tid; t < TI * C; t += 256) {
        int r = t / C, c = t % C;
        qs[r][c] = X[((size_t)b * NN + i0 + r) * C + c];
    }
    if (tid < TI) qsq[tid] = sq[b * NN + i0 + tid];
    __syncthreads();

    // ---- distance phase: d[r][p] = d2(query r, point j=tid+256p)
    float d[TI][8];
#pragma unroll
    for (int r = 0; r < TI; r++)
#pragma unroll
        for (int p = 0; p < 8; p++) d[r][p] = 0.f;

    const float* xtb = XT + (size_t)b * C * NN;
    for (int c = 0; c < C; c++) {
        float xv[8];
#pragma unroll
        for (int p = 0; p < 8; p++) xv[p] = xtb[(size_t)c * NN + tid + 256 * p];
#pragma unroll
        for (int r = 0; r < TI; r++) {
            float q = qs[r][c];
#pragma unroll
            for (int p = 0; p < 8; p++) d[r][p] += q * xv[p];
        }
    }
#pragma unroll
    for (int p = 0; p < 8; p++) {
        float sj = sq[b * NN + tid + 256 * p];
#pragma unroll
        for (int r = 0; r < TI; r++) d[r][p] = qsq[r] + sj - 2.f * d[r][p];
    }

    // ---- selection phase: 2 passes x 4 rows, one row per wave
    int wv_id = tid >> 6, lane = tid & 63;
    for (int pass = 0; pass < 2; pass++) {
        if (pass) __syncthreads();             // waves done reading dl
#pragma unroll
        for (int rr = 0; rr < 4; rr++) {
            int r = pass * 4 + rr;
#pragma unroll
            for (int p = 0; p < 8; p++)
                dl[rr][tid + 256 * p] = d[r][p];
        }
        __syncthreads();

        int row = b * NN + i0 + pass * 4 + wv_id;
        // initial per-lane min over its 32 candidates: j = 256*q + lane*4 + e
        float lv = 3.4e38f; int li = 0x7fffffff;
#pragma unroll
        for (int q = 0; q < 8; q++) {
            float4 vv = *(const float4*)&dl[wv_id][256 * q + lane * 4];
            const float* vp = (const float*)&vv;
#pragma unroll
            for (int e = 0; e < 4; e++) {
                int j = 256 * q + lane * 4 + e;
                if (vp[e] < lv) { lv = vp[e]; li = j; }   // scan order = idx asc
            }
        }

        for (int it = 0; it < KNN + 1; it++) {
            // wave-min of lv (all lanes end up with the min)
            float wvv = lv;
#pragma unroll
            for (int s = 32; s; s >>= 1)
                wvv = fminf(wvv, __shfl_xor(wvv, s));
            // find winner index (idx-asc tie-break across lanes)
            unsigned long long mask = __ballot(lv == wvv);
            int ownerlane = __ffsll((unsigned long long)mask) - 1;
            int wj = __shfl(li, ownerlane);
            if (__popcll(mask) > 1) {          // rare exact-tie path
                int cand = (lv == wvv) ? li : 0x7fffffff;
#pragma unroll
                for (int s = 32; s; s >>= 1)
                    cand = min(cand, __shfl_xor(cand, s));
                wj = cand;
            }
            if (it > 0 && lane == 0)
                idxout[(size_t)row * KNN + (it - 1)] = wj;
            // owner clears the winner and rescans its 32 candidates
            if (lane == ((wj >> 2) & 63)) {
                dl[wv_id][wj] = 3.4e38f;
                lv = 3.4e38f; li = 0x7fffffff;
#pragma unroll
                for (int q = 0; q < 8; q++) {
                    float4 vv = *(const float4*)&dl[wv_id][256 * q + lane * 4];
                    const float* vp = (const float*)&vv;
#pragma unroll
                    for (int e = 0; e < 4; e++) {
                        int j = 256 * q + lane * 4 + e;
                        if (vp[e] < lv) { lv = vp[e]; li = j; }
                    }
                }
            }
        }
    }
}

// ---------------------------------------------------------------- GEMM
// out = act( [A1|A2](M x K1+K2) @ W(:, slice) + bias + Mx ).
// FINAL=0: fp32 out. FINAL=1: dtype per *dflag (1=fp32, 0=bf16), NaN->333.
template<bool RELU, int FINAL, bool ADDMX, bool HASBIAS>
__global__ __launch_bounds__(256)
void gemm_kernel(const float* __restrict__ A1, int K1,
                 const float* __restrict__ A2, int K2,
                 const float* __restrict__ W, int ldw,
                 const float* __restrict__ bias,
                 const float* __restrict__ Mx, int ldmx,
                 void* __restrict__ out, int ldo, int col_off,
                 const int* __restrict__ dflag) {
    const int Kdim = K1 + K2;
    __shared__ __align__(16) float As[16][68];
    __shared__ __align__(16) float Bs[16][68];
    int f32o = FINAL ? *dflag : 1;
    int tid = threadIdx.x;
    int tx = tid % 16, ty = tid / 16;
    int bm = blockIdx.y * 64, bn = blockIdx.x * 64;
    float acc[4][4] = {};
    for (int k0 = 0; k0 < Kdim; k0 += 16) {
        for (int e = tid; e < 64 * 16; e += 256) {
            int row = e >> 4, col = e & 15;
            int k = k0 + col;
            float v = 0.f;
            if (k < K1)        v = A1[(size_t)(bm + row) * K1 + k];
            else if (k < Kdim) v = A2[(size_t)(bm + row) * K2 + (k - K1)];
            As[col][row] = v;
        }
        for (int e = tid; e < 16 * 64; e += 256) {
            int row = e >> 6, col = e & 63;
            int k = k0 + row;
            Bs[row][col] = (k < Kdim) ? W[(size_t)k * ldw + bn + col] : 0.f;
        }
        __syncthreads();
#pragma unroll
        for (int kk = 0; kk < 16; kk++) {
            float4 av = *(const float4*)&As[kk][ty * 4];
            float4 bv = *(const float4*)&Bs[kk][tx * 4];
            float a[4] = {av.x, av.y, av.z, av.w};
            float bb[4] = {bv.x, bv.y, bv.z, bv.w};
#pragma unroll
            for (int i = 0; i < 4; i++)
#pragma unroll
                for (int j = 0; j < 4; j++) acc[i][j] += a[i] * bb[j];
        }
        __syncthreads();
    }
#pragma unroll
    for (int i = 0; i < 4; i++) {
        int row = bm + ty * 4 + i;
        int col0 = bn + tx * 4;
        float o[4];
#pragma unroll
        for (int j = 0; j < 4; j++) {
            o[j] = acc[i][j];
            if (HASBIAS) o[j] += bias[col0 + j];
            if (ADDMX)   o[j] += Mx[(size_t)row * ldmx + col0 + j];
            if (RELU)    o[j] = fmaxf(o[j], 0.f);
            if (FINAL)   o[j] = (o[j] != o[j]) ? 333.0f : o[j];
        }
        if (FINAL) {
            if (f32o) {
                float* op = (float*)out + (size_t)row * ldo + col_off + col0;
                float4 ov = {o[0], o[1], o[2], o[3]};
                *(float4*)op = ov;
            } else {
                __hip_bfloat16* op = (__hip_bfloat16*)out + (size_t)row * ldo + col_off + col0;
#pragma unroll
                for (int j = 0; j < 4; j++) op[j] = __float2bfloat16(o[j]);
            }
        } else {
            float4 ov = {o[0], o[1], o[2], o[3]};
            *(float4*)((float*)out + (size_t)row * ldo + col0) = ov;
        }
    }
}

// ---------------------------------------------------------------- gather-max
__global__ void gather_kernel(const float* __restrict__ Cc, const int* __restrict__ idx,
                              float* __restrict__ Mx, int CW) {
    int L = blockIdx.x;
    int b = L & 7;                 // XCD swizzle: batch b -> XCD b (L2 locality)
    int i = L >> 3;
    int row = b * NN + i;
    int ch = threadIdx.x;
    __shared__ int sidx[KNN];
    if (ch < KNN) sidx[ch] = idx[(size_t)row * KNN + ch] & (NN - 1);  // clamp
    __syncthreads();
    const float* cbase = Cc + (size_t)b * NN * CW;
    float m = -3.4e38f;
#pragma unroll 4
    for (int t = 0; t < KNN; t++) {
        int j = sidx[t];
        m = fmaxf(m, cbase[(size_t)j * CW + ch]);
    }
    Mx[(size_t)row * CW + ch] = m;
}

// ---------------------------------------------------------------- launch
extern "C" void kernel_launch(void* const* d_in, const int* in_sizes, int n_in,
                              void* d_out, int out_size, void* d_ws, size_t ws_size,
                              hipStream_t stream) {
    const void* x  = d_in[0];
    const void* W1 = d_in[1];
    const void* b1 = d_in[2];
    const void* W2 = d_in[3];
    const void* b2 = d_in[4];
    const void* W3 = d_in[5];
    const void* b3 = d_in[6];

    const size_t WEIGHTS = (size_t)(3*64*2 + 64) + (64*128*2 + 128) + (192*512*2 + 512);
    const size_t fixed   = (size_t)MM*64 + (size_t)MM*128 + (size_t)MM*32 + WEIGHTS + 16;
    const size_t need64  = (fixed + (size_t)MM*2*64)  * 4;
    const size_t need128 = (fixed + (size_t)MM*2*128) * 4;

    if (d_ws == nullptr || ws_size < need64) {
        float marker = 100.0f + (float)(ws_size >> 20);
        diag_fill_kernel<<<(out_size + 255) / 256, 256, 0, stream>>>(
            (__hip_bfloat16*)d_out, out_size, marker);
        return;
    }
    const int CW = (ws_size >= need128) ? 128 : 64;

    float* ws = (float*)d_ws;
    size_t o = 0;
    float* X1   = ws + o; o += (size_t)MM * 64;
    float* X2   = ws + o; o += (size_t)MM * 128;
    float* Cch  = ws + o; o += (size_t)MM * CW;
    float* Mx   = ws + o; o += (size_t)MM * CW;
    float* Wa1  = ws + o; o += 3 * 64;
    float* Wc1  = ws + o; o += 3 * 64;
    float* bf1  = ws + o; o += 64;
    float* Wa2  = ws + o; o += 64 * 128;
    float* Wc2  = ws + o; o += 64 * 128;
    float* bf2  = ws + o; o += 128;
    float* Wa3  = ws + o; o += 192 * 512;
    float* Wc3  = ws + o; o += 192 * 512;
    float* bf3  = ws + o; o += 512;
    int*   idxb = (int*)(ws + o); o += (size_t)MM * KNN;
    int*   dflag = (int*)(ws + o); o += 16;

    // XT / X0 / SQ live in d_out: dead before any final output write.
    float* XT = (float*)d_out;                         // MM*128 floats max
    float* X0 = XT + (size_t)MM * 128;                 // MM*3 floats
    float* SQ = X0 + (size_t)MM * 3;                   // MM floats

    // dtype detect + prep
    detect_dtype_kernel<<<1, 256, 0, stream>>>((const unsigned short*)x, 24576, dflag);
    upcast_kernel<<<(MM * 3 + 255) / 256, 256, 0, stream>>>(x, X0, MM * 3, dflag);
    prep_w_kernel<<<1,   256, 0, stream>>>(W1, b1, Wa1, Wc1, bf1, 3, 64, dflag);
    prep_w_kernel<<<32,  256, 0, stream>>>(W2, b2, Wa2, Wc2, bf2, 64, 128, dflag);
    prep_w_kernel<<<384, 256, 0, stream>>>(W3, b3, Wa3, Wc3, bf3, 192, 512, dflag);

    // Chunked EdgeConv tail.
    auto edge_tail = [&](const float* A1, int K1, const float* A2, int K2,
                         const float* Wa, const float* Wc, const float* bfp, int Cout,
                         void* outp, int ldo, bool relu, bool final) {
        for (int n0 = 0; n0 < Cout; ) {
            int w = Cout - n0 < CW ? Cout - n0 : CW;
            dim3 g(w / 64, MM / 64);
            gemm_kernel<false, 0, false, false><<<g, 256, 0, stream>>>(
                A1, K1, A2, K2, Wc + n0, Cout, nullptr, nullptr, 0,
                (void*)Cch, w, 0, dflag);
            gather_kernel<<<MM, w, 0, stream>>>(Cch, idxb, Mx, w);
            if (final) {
                gemm_kernel<false, 1, true, true><<<g, 256, 0, stream>>>(
                    A1, K1, A2, K2, Wa + n0, Cout, bfp + n0, Mx, w,
                    outp, ldo, n0, dflag);
            } else {
                void* op = (void*)((float*)outp + n0);
                if (relu)
                    gemm_kernel<true, 0, true, true><<<g, 256, 0, stream>>>(
                        A1, K1, A2, K2, Wa + n0, Cout, bfp + n0, Mx, w, op, ldo, 0, dflag);
                else
                    gemm_kernel<false, 0, true, true><<<g, 256, 0, stream>>>(
                        A1, K1, A2, K2, Wa + n0, Cout, bfp + n0, Mx, w, op, ldo, 0, dflag);
            }
            n0 += w;
        }
    };

    // ---- stage 1 (C=3 -> 64)
    sqnorm_kernel<<<MM / 256, 256, 0, stream>>>(X0, SQ, 3);
    transpose_kernel<<<dim3(NN / 32, 1, BB), dim3(32, 8), 0, stream>>>(X0, XT, 3);
    knn_kernel<<<MM / TI, 256, 0, stream>>>(X0, XT, SQ, 3, idxb);
    edge_tail(X0, 3, nullptr, 0, Wa1, Wc1, bf1, 64, (void*)X1, 64, true, false);

    // ---- stage 2 (C=64 -> 128)
    sqnorm_kernel<<<MM / 256, 256, 0, stream>>>(X1, SQ, 64);
    transpose_kernel<<<dim3(NN / 32, 2, BB), dim3(32, 8), 0, stream>>>(X1, XT, 64);
    knn_kernel<<<MM / TI, 256, 0, stream>>>(X1, XT, SQ, 64, idxb);
    edge_tail(X1, 64, nullptr, 0, Wa2, Wc2, bf2, 128, (void*)X2, 128, true, false);

    // ---- stage 3 (C=192 = [X1|X2] -> 512, no relu, final out)
    sqnorm_kernel<<<MM / 256, 256, 0, stream>>>(X2, SQ, 128);
    transpose_kernel<<<dim3(NN / 32, 4, BB), dim3(32, 8), 0, stream>>>(X2, XT, 128);
    knn_kernel<<<MM / TI, 256, 0, stream>>>(X2, XT, SQ, 128, idxb);
    edge_tail(X1, 64, X2, 128, Wa3, Wc3, bf3, 512, d_out, 512, false, true);
}

// Round 7
// 1059.436 us; speedup vs baseline: 2.2742x; 1.0606x over previous
//
#include <hip/hip_runtime.h>
#include <hip/hip_bf16.h>

#define BB 8
#define NN 2048
#define MM (BB*NN)
#define KNN 32
#define TI 8

// ---------------------------------------------------------------- dtype detect
__global__ void detect_dtype_kernel(const unsigned short* __restrict__ p,
                                    int n16, int* __restrict__ flag) {
    __shared__ int cnt;
    if (threadIdx.x == 0) cnt = 0;
    __syncthreads();
    int local = 0;
    for (int i = threadIdx.x; i < n16; i += 256) {
        int e = (p[i] >> 7) & 0xFF;
        if (e >= 132) local++;     // |v| >= 2^5, or inf/nan
    }
    atomicAdd(&cnt, local);
    __syncthreads();
    if (threadIdx.x == 0) *flag = (cnt > 100) ? 1 : 0;   // 1 = fp32 inputs
}

// ---------------------------------------------------------------- diagnostic
__global__ void diag_fill_kernel(__hip_bfloat16* __restrict__ out, int n, float marker) {
    int i = blockIdx.x * 256 + threadIdx.x;
    if (i < n) out[i] = __float2bfloat16(marker);
}

// ---------------------------------------------------------------- utilities
__global__ void upcast_kernel(const void* __restrict__ in, float* __restrict__ out,
                              int n, const int* __restrict__ flag) {
    int f32 = *flag;
    int i = blockIdx.x * 256 + threadIdx.x;
    if (i < n)
        out[i] = f32 ? ((const float*)in)[i]
                     : __bfloat162float(((const __hip_bfloat16*)in)[i]);
}

// W: (2C, Cout) -> Wa = Wtop - Wbot, Wc = Wbot (C x Cout fp32), bf = bias.
// EdgeConv decomposition:
//   max_j act([x_i, x_j - x_i] W + b) = act(x_i Wa + b + max_j (x_j Wc))
__global__ void prep_w_kernel(const void* __restrict__ W, const void* __restrict__ bvec,
                              float* __restrict__ Wa, float* __restrict__ Wc,
                              float* __restrict__ bf, int C, int Cout,
                              const int* __restrict__ flag) {
    int f32 = *flag;
    int total = C * Cout;
    int gid = blockIdx.x * 256 + threadIdx.x;
    for (int t = gid; t < total; t += gridDim.x * 256) {
        int k = t / Cout, n = t % Cout;
        float top, bot;
        if (f32) {
            top = ((const float*)W)[k * Cout + n];
            bot = ((const float*)W)[(C + k) * Cout + n];
        } else {
            top = __bfloat162float(((const __hip_bfloat16*)W)[k * Cout + n]);
            bot = __bfloat162float(((const __hip_bfloat16*)W)[(C + k) * Cout + n]);
        }
        Wa[t] = top - bot;
        Wc[t] = bot;
    }
    if (gid < Cout)
        bf[gid] = f32 ? ((const float*)bvec)[gid]
                      : __bfloat162float(((const __hip_bfloat16*)bvec)[gid]);
}

__global__ void sqnorm_kernel(const float* __restrict__ X, float* __restrict__ sq, int C) {
    int row = blockIdx.x * 256 + threadIdx.x;
    if (row < MM) {
        float s = 0.f;
        for (int c = 0; c < C; c++) { float v = X[(size_t)row * C + c]; s += v * v; }
        sq[row] = s;
    }
}

// X (B,N,C) -> XT (B,C,N)
__global__ void transpose_kernel(const float* __restrict__ X, float* __restrict__ XT, int C) {
    __shared__ float tile[32][33];
    int b = blockIdx.z;
    int n0 = blockIdx.x * 32, c0 = blockIdx.y * 32;
    int tx = threadIdx.x, ty = threadIdx.y;   // 32 x 8
    for (int k = 0; k < 32; k += 8) {
        int n = n0 + ty + k, c = c0 + tx;
        tile[ty + k][tx] = (c < C) ? X[((size_t)b * NN + n) * C + c] : 0.f;
    }
    __syncthreads();
    for (int k = 0; k < 32; k += 8) {
        int c = c0 + ty + k, n = n0 + tx;
        if (c < C) XT[((size_t)b * C + c) * NN + n] = tile[tx][ty + k];
    }
}

// ---------------------------------------------------------------- kNN
// Distance phase: block computes d[8 rows][2048 pts] register-tiled. Selection:
// distances to LDS 4 rows/pass, one wave per row; per-lane TOP-2 cache
// (m1,i1,m2,i2) over its 32 candidates (j = lane + 64q, conflict-free b32).
// Extraction: fmin butterfly on m1, ballot->owner, owner marks LDS INF and
// promotes m2; full 32-value rescan only when a lane's 2nd entry is consumed
// (~6x/row instead of 33x/row).
__global__ __launch_bounds__(256)
void knn_kernel(const float* __restrict__ X, const float* __restrict__ XT,
                const float* __restrict__ sq, int C, int* __restrict__ idxout) {
    int b = blockIdx.x & 7;                    // XCD swizzle: batch -> XCD
    int i0 = (blockIdx.x >> 3) * TI;
    int tid = threadIdx.x;
    __shared__ float qs[TI][128];
    __shared__ float qsq[TI];
    __shared__ __align__(16) float dl[4][NN];  // 32 KB: 4 rows per pass

    for (int t = tid; t < TI * C; t += 256) {
        int r = t / C, c = t % C;
        qs[r][c] = X[((size_t)b * NN + i0 + r) * C + c];
    }
    if (tid < TI) qsq[tid] = sq[b * NN + i0 + tid];
    __syncthreads();

    // ---- distance phase: d[r][p] = d2(query r, point j=tid+256p)
    float d[TI][8];
#pragma unroll
    for (int r = 0; r < TI; r++)
#pragma unroll
        for (int p = 0; p < 8; p++) d[r][p] = 0.f;

    const float* xtb = XT + (size_t)b * C * NN;
    for (int c = 0; c < C; c++) {
        float xv[8];
#pragma unroll
        for (int p = 0; p < 8; p++) xv[p] = xtb[(size_t)c * NN + tid + 256 * p];
#pragma unroll
        for (int r = 0; r < TI; r++) {
            float q = qs[r][c];
#pragma unroll
            for (int p = 0; p < 8; p++) d[r][p] += q * xv[p];
        }
    }
#pragma unroll
    for (int p = 0; p < 8; p++) {
        float sj = sq[b * NN + tid + 256 * p];
#pragma unroll
        for (int r = 0; r < TI; r++) d[r][p] = qsq[r] + sj - 2.f * d[r][p];
    }

    // ---- selection phase: 2 passes x 4 rows, one row per wave
    int wv_id = tid >> 6, lane = tid & 63;
    const float INF = 3.4e38f;
    for (int pass = 0; pass < 2; pass++) {
        if (pass) __syncthreads();             // waves done reading dl
#pragma unroll
        for (int rr = 0; rr < 4; rr++) {
            int r = pass * 4 + rr;
#pragma unroll
            for (int p = 0; p < 8; p++)
                dl[rr][tid + 256 * p] = d[r][p];
        }
        __syncthreads();

        int row = b * NN + i0 + pass * 4 + wv_id;
        float* dr = dl[wv_id];
        // build top-2 over lane's candidates j = lane + 64q (scan = idx asc)
        float m1 = INF, m2 = INF; int i1 = 0x7fffffff, i2 = 0x7fffffff;
#pragma unroll
        for (int q = 0; q < 32; q++) {
            int j = lane + 64 * q;
            float v = dr[j];
            if (v < m1)      { m2 = m1; i2 = i1; m1 = v; i1 = j; }
            else if (v < m2) { m2 = v; i2 = j; }
        }

        for (int it = 0; it < KNN + 1; it++) {
            float wvv = m1;
#pragma unroll
            for (int s = 32; s; s >>= 1)
                wvv = fminf(wvv, __shfl_xor(wvv, s));
            unsigned long long mask = __ballot(m1 == wvv);
            int ownerlane = __ffsll(mask) - 1;
            int wj = __shfl(i1, ownerlane);
            if (__popcll(mask) > 1) {          // rare exact-tie path: idx-asc
                int cand = (m1 == wvv) ? i1 : 0x7fffffff;
#pragma unroll
                for (int s = 32; s; s >>= 1)
                    cand = min(cand, __shfl_xor(cand, s));
                wj = cand;
            }
            if (it > 0 && lane == 0)
                idxout[(size_t)row * KNN + (it - 1)] = wj;
            if (i1 == wj) {                    // unique owner (wj & 63 == lane)
                dr[wj] = INF;                  // keep LDS copy consistent
                if (i2 != -1) { m1 = m2; i1 = i2; i2 = -1; }
                else {                          // standby empty: rescan 32
                    m1 = INF; m2 = INF; i1 = 0x7fffffff; i2 = 0x7fffffff;
#pragma unroll
                    for (int q = 0; q < 32; q++) {
                        int j = lane + 64 * q;
                        float v = dr[j];
                        if (v < m1)      { m2 = m1; i2 = i1; m1 = v; i1 = j; }
                        else if (v < m2) { m2 = v; i2 = j; }
                    }
                }
            }
        }
    }
}

// ---------------------------------------------------------------- dual GEMM
// Cc = [A1|A2] @ Wc(:, slice)          (raw, for gather-max)
// Ap = [A1|A2] @ Wa(:, slice) + bias   (self part, act applied later)
// BM=64, BN=64 (x2 outputs), BK=16, 256 thr, 4x4+4x4 micro-tile.
__global__ __launch_bounds__(256)
void gemm_dual(const float* __restrict__ A1, int K1,
               const float* __restrict__ A2, int K2,
               const float* __restrict__ Wc, const float* __restrict__ Wa,
               int ldw, const float* __restrict__ bias,
               float* __restrict__ Cc, float* __restrict__ Ap, int w) {
    const int Kdim = K1 + K2;
    __shared__ __align__(16) float As[16][68];
    __shared__ __align__(16) float Bs[16][136];   // [0,64)=Wc  [64,128)=Wa
    int tid = threadIdx.x;
    int tx = tid % 16, ty = tid / 16;
    int bm = blockIdx.y * 64, bn = blockIdx.x * 64;
    float accC[4][4] = {}, accA[4][4] = {};
    for (int k0 = 0; k0 < Kdim; k0 += 16) {
        for (int e = tid; e < 64 * 16; e += 256) {
            int row = e >> 4, col = e & 15;
            int k = k0 + col;
            float v = 0.f;
            if (k < K1)        v = A1[(size_t)(bm + row) * K1 + k];
            else if (k < Kdim) v = A2[(size_t)(bm + row) * K2 + (k - K1)];
            As[col][row] = v;
        }
        for (int e = tid; e < 16 * 64; e += 256) {
            int row = e >> 6, col = e & 63;
            int k = k0 + row;
            float vc = 0.f, va = 0.f;
            if (k < Kdim) {
                vc = Wc[(size_t)k * ldw + bn + col];
                va = Wa[(size_t)k * ldw + bn + col];
            }
            Bs[row][col] = vc;
            Bs[row][64 + col] = va;
        }
        __syncthreads();
#pragma unroll
        for (int kk = 0; kk < 16; kk++) {
            float4 av = *(const float4*)&As[kk][ty * 4];
            float4 bc = *(const float4*)&Bs[kk][tx * 4];
            float4 ba = *(const float4*)&Bs[kk][64 + tx * 4];
            float a[4]  = {av.x, av.y, av.z, av.w};
            float c[4]  = {bc.x, bc.y, bc.z, bc.w};
            float aa[4] = {ba.x, ba.y, ba.z, ba.w};
#pragma unroll
            for (int i = 0; i < 4; i++)
#pragma unroll
                for (int j = 0; j < 4; j++) {
                    accC[i][j] += a[i] * c[j];
                    accA[i][j] += a[i] * aa[j];
                }
        }
        __syncthreads();
    }
#pragma unroll
    for (int i = 0; i < 4; i++) {
        int row = bm + ty * 4 + i;
        int col0 = bn + tx * 4;
        float4 oc = {accC[i][0], accC[i][1], accC[i][2], accC[i][3]};
        *(float4*)&Cc[(size_t)row * w + col0] = oc;
        float4 oa = {accA[i][0] + bias[col0 + 0], accA[i][1] + bias[col0 + 1],
                     accA[i][2] + bias[col0 + 2], accA[i][3] + bias[col0 + 3]};
        *(float4*)&Ap[(size_t)row * w + col0] = oa;
    }
}

// ---------------------------------------------------------------- gather+epilogue
// out[row][col_off+ch] = act( Ap[row][ch] + max_j Cc[nbr_j][ch] )
template<int FINAL>
__global__ void gather_fuse(const float* __restrict__ Cc, const float* __restrict__ Ap,
                            const int* __restrict__ idx, int w,
                            void* __restrict__ out, int ldo, int col_off, int relu,
                            const int* __restrict__ dflag) {
    int L = blockIdx.x;
    int b = L & 7;                 // XCD swizzle: batch b -> XCD b (L2 locality)
    int i = L >> 3;
    int row = b * NN + i;
    int ch = threadIdx.x;
    __shared__ int sidx[KNN];
    if (ch < KNN) sidx[ch] = idx[(size_t)row * KNN + ch] & (NN - 1);
    __syncthreads();
    const float* cbase = Cc + (size_t)b * NN * w;
    float m = -3.4e38f;
#pragma unroll 4
    for (int t = 0; t < KNN; t++)
        m = fmaxf(m, cbase[(size_t)sidx[t] * w + ch]);
    float r = Ap[(size_t)row * w + ch] + m;
    if (relu) r = fmaxf(r, 0.f);
    if (FINAL) {
        r = (r != r) ? 333.0f : r;
        if (*dflag)
            ((float*)out)[(size_t)row * ldo + col_off + ch] = r;
        else
            ((__hip_bfloat16*)out)[(size_t)row * ldo + col_off + ch] = __float2bfloat16(r);
    } else {
        ((float*)out)[(size_t)row * ldo + col_off + ch] = r;
    }
}

// ---------------------------------------------------------------- launch
extern "C" void kernel_launch(void* const* d_in, const int* in_sizes, int n_in,
                              void* d_out, int out_size, void* d_ws, size_t ws_size,
                              hipStream_t stream) {
    const void* x  = d_in[0];
    const void* W1 = d_in[1];
    const void* b1 = d_in[2];
    const void* W2 = d_in[3];
    const void* b2 = d_in[4];
    const void* W3 = d_in[5];
    const void* b3 = d_in[6];

    const size_t WEIGHTS = (size_t)(3*64*2 + 64) + (64*128*2 + 128) + (192*512*2 + 512);
    const size_t fixed   = (size_t)MM*64 + (size_t)MM*128 + (size_t)MM*32 + WEIGHTS + 16;
    const size_t need64  = (fixed + (size_t)MM*2*64)  * 4;
    const size_t need128 = (fixed + (size_t)MM*2*128) * 4;

    if (d_ws == nullptr || ws_size < need64) {
        float marker = 100.0f + (float)(ws_size >> 20);
        diag_fill_kernel<<<(out_size + 255) / 256, 256, 0, stream>>>(
            (__hip_bfloat16*)d_out, out_size, marker);
        return;
    }
    const int CW = (ws_size >= need128) ? 128 : 64;

    float* ws = (float*)d_ws;
    size_t o = 0;
    float* X1   = ws + o; o += (size_t)MM * 64;
    float* X2   = ws + o; o += (size_t)MM * 128;
    float* Cc   = ws + o; o += (size_t)MM * CW;
    float* Ap   = ws + o; o += (size_t)MM * CW;
    float* Wa1  = ws + o; o += 3 * 64;
    float* Wc1  = ws + o; o += 3 * 64;
    float* bf1  = ws + o; o += 64;
    float* Wa2  = ws + o; o += 64 * 128;
    float* Wc2  = ws + o; o += 64 * 128;
    float* bf2  = ws + o; o += 128;
    float* Wa3  = ws + o; o += 192 * 512;
    float* Wc3  = ws + o; o += 192 * 512;
    float* bf3  = ws + o; o += 512;
    int*   idxb = (int*)(ws + o); o += (size_t)MM * KNN;
    int*   dflag = (int*)(ws + o); o += 16;

    // XT / X0 / SQ live in d_out: dead before any final output write.
    float* XT = (float*)d_out;                         // MM*128 floats max
    float* X0 = XT + (size_t)MM * 128;                 // MM*3 floats
    float* SQ = X0 + (size_t)MM * 3;                   // MM floats

    // dtype detect + prep
    detect_dtype_kernel<<<1, 256, 0, stream>>>((const unsigned short*)x, 24576, dflag);
    upcast_kernel<<<(MM * 3 + 255) / 256, 256, 0, stream>>>(x, X0, MM * 3, dflag);
    prep_w_kernel<<<1,   256, 0, stream>>>(W1, b1, Wa1, Wc1, bf1, 3, 64, dflag);
    prep_w_kernel<<<32,  256, 0, stream>>>(W2, b2, Wa2, Wc2, bf2, 64, 128, dflag);
    prep_w_kernel<<<384, 256, 0, stream>>>(W3, b3, Wa3, Wc3, bf3, 192, 512, dflag);

    // Chunked EdgeConv tail: per chunk of width w:
    //   gemm_dual: Cc = X@Wc_slice, Ap = X@Wa_slice + b
    //   gather_fuse: out = act(Ap + gather-max(Cc))
    auto edge_tail = [&](const float* A1, int K1, const float* A2, int K2,
                         const float* Wa, const float* Wc, const float* bfp, int Cout,
                         void* outp, int ldo, int relu, bool final) {
        for (int n0 = 0; n0 < Cout; ) {
            int w = Cout - n0 < CW ? Cout - n0 : CW;
            dim3 g(w / 64, MM / 64);
            gemm_dual<<<g, 256, 0, stream>>>(A1, K1, A2, K2, Wc + n0, Wa + n0,
                                             Cout, bfp + n0, Cc, Ap, w);
            if (final)
                gather_fuse<1><<<MM, w, 0, stream>>>(Cc, Ap, idxb, w, outp, ldo,
                                                     n0, relu, dflag);
            else
                gather_fuse<0><<<MM, w, 0, stream>>>(Cc, Ap, idxb, w, outp, ldo,
                                                     n0, relu, dflag);
            n0 += w;
        }
    };

    // ---- stage 1 (C=3 -> 64)
    sqnorm_kernel<<<MM / 256, 256, 0, stream>>>(X0, SQ, 3);
    transpose_kernel<<<dim3(NN / 32, 1, BB), dim3(32, 8), 0, stream>>>(X0, XT, 3);
    knn_kernel<<<MM / TI, 256, 0, stream>>>(X0, XT, SQ, 3, idxb);
    edge_tail(X0, 3, nullptr, 0, Wa1, Wc1, bf1, 64, (void*)X1, 64, 1, false);

    // ---- stage 2 (C=64 -> 128)
    sqnorm_kernel<<<MM / 256, 256, 0, stream>>>(X1, SQ, 64);
    transpose_kernel<<<dim3(NN / 32, 2, BB), dim3(32, 8), 0, stream>>>(X1, XT, 64);
    knn_kernel<<<MM / TI, 256, 0, stream>>>(X1, XT, SQ, 64, idxb);
    edge_tail(X1, 64, nullptr, 0, Wa2, Wc2, bf2, 128, (void*)X2, 128, 1, false);

    // ---- stage 3 (C=192 = [X1|X2] -> 512, no relu, final out)
    sqnorm_kernel<<<MM / 256, 256, 0, stream>>>(X2, SQ, 128);
    transpose_kernel<<<dim3(NN / 32, 4, BB), dim3(32, 8), 0, stream>>>(X2, XT, 128);
    knn_kernel<<<MM / TI, 256, 0, stream>>>(X2, XT, SQ, 128, idxb);
    edge_tail(X1, 64, X2, 128, Wa3, Wc3, bf3, 512, d_out, 512, 0, true);
}

// Round 8
// 1023.311 us; speedup vs baseline: 2.3545x; 1.0353x over previous
//
#include <hip/hip_runtime.h>
#include <hip/hip_bf16.h>

#define BB 8
#define NN 2048
#define MM (BB*NN)
#define KNN 32
#define TI 8

// ---------------------------------------------------------------- dtype detect
__global__ void detect_dtype_kernel(const unsigned short* __restrict__ p,
                                    int n16, int* __restrict__ flag) {
    __shared__ int cnt;
    if (threadIdx.x == 0) cnt = 0;
    __syncthreads();
    int local = 0;
    for (int i = threadIdx.x; i < n16; i += 256) {
        int e = (p[i] >> 7) & 0xFF;
        if (e >= 132) local++;     // |v| >= 2^5, or inf/nan
    }
    atomicAdd(&cnt, local);
    __syncthreads();
    if (threadIdx.x == 0) *flag = (cnt > 100) ? 1 : 0;   // 1 = fp32 inputs
}

// ---------------------------------------------------------------- diagnostic
__global__ void diag_fill_kernel(__hip_bfloat16* __restrict__ out, int n, float marker) {
    int i = blockIdx.x * 256 + threadIdx.x;
    if (i < n) out[i] = __float2bfloat16(marker);
}

// ---------------------------------------------------------------- utilities
__global__ void upcast_kernel(const void* __restrict__ in, float* __restrict__ out,
                              int n, const int* __restrict__ flag) {
    int f32 = *flag;
    int i = blockIdx.x * 256 + threadIdx.x;
    if (i < n)
        out[i] = f32 ? ((const float*)in)[i]
                     : __bfloat162float(((const __hip_bfloat16*)in)[i]);
}

// W: (2C, Cout) -> Wa = Wtop - Wbot, Wc = Wbot (C x Cout fp32), bf = bias.
// EdgeConv decomposition:
//   max_j act([x_i, x_j - x_i] W + b) = act(x_i Wa + b + max_j (x_j Wc))
__global__ void prep_w_kernel(const void* __restrict__ W, const void* __restrict__ bvec,
                              float* __restrict__ Wa, float* __restrict__ Wc,
                              float* __restrict__ bf, int C, int Cout,
                              const int* __restrict__ flag) {
    int f32 = *flag;
    int total = C * Cout;
    int gid = blockIdx.x * 256 + threadIdx.x;
    for (int t = gid; t < total; t += gridDim.x * 256) {
        int k = t / Cout, n = t % Cout;
        float top, bot;
        if (f32) {
            top = ((const float*)W)[k * Cout + n];
            bot = ((const float*)W)[(C + k) * Cout + n];
        } else {
            top = __bfloat162float(((const __hip_bfloat16*)W)[k * Cout + n]);
            bot = __bfloat162float(((const __hip_bfloat16*)W)[(C + k) * Cout + n]);
        }
        Wa[t] = top - bot;
        Wc[t] = bot;
    }
    if (gid < Cout)
        bf[gid] = f32 ? ((const float*)bvec)[gid]
                      : __bfloat162float(((const __hip_bfloat16*)bvec)[gid]);
}

__global__ void sqnorm_kernel(const float* __restrict__ X, float* __restrict__ sq, int C) {
    int row = blockIdx.x * 256 + threadIdx.x;
    if (row < MM) {
        float s = 0.f;
        for (int c = 0; c < C; c++) { float v = X[(size_t)row * C + c]; s += v * v; }
        sq[row] = s;
    }
}

// X (B,N,C) -> XT (B,C,N)
__global__ void transpose_kernel(const float* __restrict__ X, float* __restrict__ XT, int C) {
    __shared__ float tile[32][33];
    int b = blockIdx.z;
    int n0 = blockIdx.x * 32, c0 = blockIdx.y * 32;
    int tx = threadIdx.x, ty = threadIdx.y;   // 32 x 8
    for (int k = 0; k < 32; k += 8) {
        int n = n0 + ty + k, c = c0 + tx;
        tile[ty + k][tx] = (c < C) ? X[((size_t)b * NN + n) * C + c] : 0.f;
    }
    __syncthreads();
    for (int k = 0; k < 32; k += 8) {
        int c = c0 + ty + k, n = n0 + tx;
        if (c < C) XT[((size_t)b * C + c) * NN + n] = tile[tx][ty + k];
    }
}

// ---------------------------------------------------------------- wave min (DPP)
// fmin reduction across 64 lanes, result broadcast via readlane(63).
// update_dpp(old=v, src=v): lanes with no source keep v -> fmin no-op.
__device__ __forceinline__ float fmin_dpp(float v, const int ctrl) {
    int y;
    switch (ctrl) {   // ctrl must be an immediate for the builtin
    case 0x111: y = __builtin_amdgcn_update_dpp(__float_as_int(v), __float_as_int(v), 0x111, 0xF, 0xF, false); break;
    case 0x112: y = __builtin_amdgcn_update_dpp(__float_as_int(v), __float_as_int(v), 0x112, 0xF, 0xF, false); break;
    case 0x114: y = __builtin_amdgcn_update_dpp(__float_as_int(v), __float_as_int(v), 0x114, 0xF, 0xF, false); break;
    case 0x118: y = __builtin_amdgcn_update_dpp(__float_as_int(v), __float_as_int(v), 0x118, 0xF, 0xF, false); break;
    case 0x142: y = __builtin_amdgcn_update_dpp(__float_as_int(v), __float_as_int(v), 0x142, 0xF, 0xF, false); break;
    default:    y = __builtin_amdgcn_update_dpp(__float_as_int(v), __float_as_int(v), 0x143, 0xF, 0xF, false); break;
    }
    return fminf(v, __int_as_float(y));
}
__device__ __forceinline__ float wave_min_bcast(float v) {
    v = fmin_dpp(v, 0x111);   // row_shr:1
    v = fmin_dpp(v, 0x112);   // row_shr:2
    v = fmin_dpp(v, 0x114);   // row_shr:4
    v = fmin_dpp(v, 0x118);   // row_shr:8  -> lane15 of each row16 has row min
    v = fmin_dpp(v, 0x142);   // row_bcast:15 -> lane31 has min of 0..31
    v = fmin_dpp(v, 0x143);   // row_bcast:31 -> lane63 has min of 0..63
    return __int_as_float(__builtin_amdgcn_readlane(__float_as_int(v), 63));
}

// ---------------------------------------------------------------- kNN
// Distance phase: d[8 rows][2048 pts] register-tiled (pass loop UNROLLED so d
// stays in VGPRs). Selection: distances to LDS 4 rows/pass, one wave per row;
// per-lane top-2 cache over candidates j = lane + 64q; extraction via DPP fmin
// reduce + readlane owner fetch (no bpermute chain); winners kept in a register
// (lane it-1) and stored coalesced.
__global__ __launch_bounds__(256)
void knn_kernel(const float* __restrict__ X, const float* __restrict__ XT,
                const float* __restrict__ sq, int C, int* __restrict__ idxout) {
    int b = blockIdx.x & 7;                    // XCD swizzle: batch -> XCD
    int i0 = (blockIdx.x >> 3) * TI;
    int tid = threadIdx.x;
    __shared__ float qs[TI][128];
    __shared__ float qsq[TI];
    __shared__ __align__(16) float dl[4][NN];  // 32 KB: 4 rows per pass

    for (int t = tid; t < TI * C; t += 256) {
        int r = t / C, c = t % C;
        qs[r][c] = X[((size_t)b * NN + i0 + r) * C + c];
    }
    if (tid < TI) qsq[tid] = sq[b * NN + i0 + tid];
    __syncthreads();

    // ---- distance phase: d[r][p] = d2(query r, point j=tid+256p)
    float d[TI][8];
#pragma unroll
    for (int r = 0; r < TI; r++)
#pragma unroll
        for (int p = 0; p < 8; p++) d[r][p] = 0.f;

    const float* xtb = XT + (size_t)b * C * NN;
    for (int c = 0; c < C; c++) {
        float xv[8];
#pragma unroll
        for (int p = 0; p < 8; p++) xv[p] = xtb[(size_t)c * NN + tid + 256 * p];
#pragma unroll
        for (int r = 0; r < TI; r++) {
            float q = qs[r][c];
#pragma unroll
            for (int p = 0; p < 8; p++) d[r][p] += q * xv[p];
        }
    }
#pragma unroll
    for (int p = 0; p < 8; p++) {
        float sj = sq[b * NN + tid + 256 * p];
#pragma unroll
        for (int r = 0; r < TI; r++) d[r][p] = qsq[r] + sj - 2.f * d[r][p];
    }

    // ---- selection phase: 2 passes x 4 rows, one wave per row (barrier-free)
    int wv_id = tid >> 6, lane = tid & 63;
    const float INF = 3.4e38f;
#pragma unroll
    for (int pass = 0; pass < 2; pass++) {     // UNROLLED: d[] indices static
        if (pass) __syncthreads();             // waves done reading dl
#pragma unroll
        for (int rr = 0; rr < 4; rr++) {
#pragma unroll
            for (int p = 0; p < 8; p++)
                dl[rr][tid + 256 * p] = d[pass * 4 + rr][p];
        }
        __syncthreads();

        int row = b * NN + i0 + pass * 4 + wv_id;
        float* dr = dl[wv_id];
        // build top-2 over lane's candidates j = lane + 64q (scan = idx asc)
        float m1 = INF, m2 = INF; int i1 = 0x7fffffff, i2 = 0x7fffffff;
#pragma unroll
        for (int q = 0; q < 32; q++) {
            int j = lane + 64 * q;
            float v = dr[j];
            if (v < m1)      { m2 = m1; i2 = i1; m1 = v; i1 = j; }
            else if (v < m2) { m2 = v; i2 = j; }
        }

        int mywj = 0;                          // per-lane winner slot (lane it-1)
        for (int it = 0; it < KNN + 1; it++) {
            float wvv = wave_min_bcast(m1);
            unsigned long long mask = __ballot(m1 == wvv);
            int ownerlane = __builtin_amdgcn_readfirstlane(__ffsll(mask) - 1);
            int wj = __builtin_amdgcn_readlane(i1, ownerlane);
            if (__popcll(mask) > 1) {          // rare exact-tie path: idx-asc
                int cand = (m1 == wvv) ? i1 : 0x7fffffff;
#pragma unroll
                for (int s = 32; s; s >>= 1)
                    cand = min(cand, __shfl_xor(cand, s));
                wj = cand;
            }
            if (lane == it - 1) mywj = wj;     // stash winner (order irrelevant for max)
            if (i1 == wj) {                    // unique owner (wj & 63 == lane)
                dr[wj] = INF;                  // keep LDS copy consistent
                if (i2 != -1) { m1 = m2; i1 = i2; i2 = -1; }
                else {                          // standby empty: rescan 32
                    m1 = INF; m2 = INF; i1 = 0x7fffffff; i2 = 0x7fffffff;
#pragma unroll
                    for (int q = 0; q < 32; q++) {
                        int j = lane + 64 * q;
                        float v = dr[j];
                        if (v < m1)      { m2 = m1; i2 = i1; m1 = v; i1 = j; }
                        else if (v < m2) { m2 = v; i2 = j; }
                    }
                }
            }
        }
        if (lane < KNN)
            idxout[(size_t)row * KNN + lane] = mywj;   // coalesced winner store
    }
}

// ---------------------------------------------------------------- dual GEMM
// Cc = [A1|A2] @ Wc(:, slice)          (raw, for gather-max)
// Ap = [A1|A2] @ Wa(:, slice) + bias   (self part, act applied later)
__global__ __launch_bounds__(256)
void gemm_dual(const float* __restrict__ A1, int K1,
               const float* __restrict__ A2, int K2,
               const float* __restrict__ Wc, const float* __restrict__ Wa,
               int ldw, const float* __restrict__ bias,
               float* __restrict__ Cc, float* __restrict__ Ap, int w) {
    const int Kdim = K1 + K2;
    __shared__ __align__(16) float As[16][68];
    __shared__ __align__(16) float Bs[16][136];   // [0,64)=Wc  [64,128)=Wa
    int tid = threadIdx.x;
    int tx = tid % 16, ty = tid / 16;
    int bm = blockIdx.y * 64, bn = blockIdx.x * 64;
    float accC[4][4] = {}, accA[4][4] = {};
    for (int k0 = 0; k0 < Kdim; k0 += 16) {
        for (int e = tid; e < 64 * 16; e += 256) {
            int row = e >> 4, col = e & 15;
            int k = k0 + col;
            float v = 0.f;
            if (k < K1)        v = A1[(size_t)(bm + row) * K1 + k];
            else if (k < Kdim) v = A2[(size_t)(bm + row) * K2 + (k - K1)];
            As[col][row] = v;
        }
        for (int e = tid; e < 16 * 64; e += 256) {
            int row = e >> 6, col = e & 63;
            int k = k0 + row;
            float vc = 0.f, va = 0.f;
            if (k < Kdim) {
                vc = Wc[(size_t)k * ldw + bn + col];
                va = Wa[(size_t)k * ldw + bn + col];
            }
            Bs[row][col] = vc;
            Bs[row][64 + col] = va;
        }
        __syncthreads();
#pragma unroll
        for (int kk = 0; kk < 16; kk++) {
            float4 av = *(const float4*)&As[kk][ty * 4];
            float4 bc = *(const float4*)&Bs[kk][tx * 4];
            float4 ba = *(const float4*)&Bs[kk][64 + tx * 4];
            float a[4]  = {av.x, av.y, av.z, av.w};
            float c[4]  = {bc.x, bc.y, bc.z, bc.w};
            float aa[4] = {ba.x, ba.y, ba.z, ba.w};
#pragma unroll
            for (int i = 0; i < 4; i++)
#pragma unroll
                for (int j = 0; j < 4; j++) {
                    accC[i][j] += a[i] * c[j];
                    accA[i][j] += a[i] * aa[j];
                }
        }
        __syncthreads();
    }
#pragma unroll
    for (int i = 0; i < 4; i++) {
        int row = bm + ty * 4 + i;
        int col0 = bn + tx * 4;
        float4 oc = {accC[i][0], accC[i][1], accC[i][2], accC[i][3]};
        *(float4*)&Cc[(size_t)row * w + col0] = oc;
        float4 oa = {accA[i][0] + bias[col0 + 0], accA[i][1] + bias[col0 + 1],
                     accA[i][2] + bias[col0 + 2], accA[i][3] + bias[col0 + 3]};
        *(float4*)&Ap[(size_t)row * w + col0] = oa;
    }
}

// ---------------------------------------------------------------- gather+epilogue
// out[row][col_off+ch] = act( Ap[row][ch] + max_j Cc[nbr_j][ch] )
template<int FINAL>
__global__ void gather_fuse(const float* __restrict__ Cc, const float* __restrict__ Ap,
                            const int* __restrict__ idx, int w,
                            void* __restrict__ out, int ldo, int col_off, int relu,
                            const int* __restrict__ dflag) {
    int L = blockIdx.x;
    int b = L & 7;                 // XCD swizzle: batch b -> XCD b (L2 locality)
    int i = L >> 3;
    int row = b * NN + i;
    int ch = threadIdx.x;
    __shared__ int sidx[KNN];
    if (ch < KNN) sidx[ch] = idx[(size_t)row * KNN + ch] & (NN - 1);
    __syncthreads();
    const float* cbase = Cc + (size_t)b * NN * w;
    float m = -3.4e38f;
#pragma unroll 4
    for (int t = 0; t < KNN; t++)
        m = fmaxf(m, cbase[(size_t)sidx[t] * w + ch]);
    float r = Ap[(size_t)row * w + ch] + m;
    if (relu) r = fmaxf(r, 0.f);
    if (FINAL) {
        r = (r != r) ? 333.0f : r;
        if (*dflag)
            ((float*)out)[(size_t)row * ldo + col_off + ch] = r;
        else
            ((__hip_bfloat16*)out)[(size_t)row * ldo + col_off + ch] = __float2bfloat16(r);
    } else {
        ((float*)out)[(size_t)row * ldo + col_off + ch] = r;
    }
}

// ---------------------------------------------------------------- launch
extern "C" void kernel_launch(void* const* d_in, const int* in_sizes, int n_in,
                              void* d_out, int out_size, void* d_ws, size_t ws_size,
                              hipStream_t stream) {
    const void* x  = d_in[0];
    const void* W1 = d_in[1];
    const void* b1 = d_in[2];
    const void* W2 = d_in[3];
    const void* b2 = d_in[4];
    const void* W3 = d_in[5];
    const void* b3 = d_in[6];

    const size_t WEIGHTS = (size_t)(3*64*2 + 64) + (64*128*2 + 128) + (192*512*2 + 512);
    const size_t fixed   = (size_t)MM*64 + (size_t)MM*128 + (size_t)MM*32 + WEIGHTS + 16;
    const size_t need64  = (fixed + (size_t)MM*2*64)  * 4;
    const size_t need128 = (fixed + (size_t)MM*2*128) * 4;

    if (d_ws == nullptr || ws_size < need64) {
        float marker = 100.0f + (float)(ws_size >> 20);
        diag_fill_kernel<<<(out_size + 255) / 256, 256, 0, stream>>>(
            (__hip_bfloat16*)d_out, out_size, marker);
        return;
    }
    const int CW = (ws_size >= need128) ? 128 : 64;

    float* ws = (float*)d_ws;
    size_t o = 0;
    float* X1   = ws + o; o += (size_t)MM * 64;
    float* X2   = ws + o; o += (size_t)MM * 128;
    float* Cc   = ws + o; o += (size_t)MM * CW;
    float* Ap   = ws + o; o += (size_t)MM * CW;
    float* Wa1  = ws + o; o += 3 * 64;
    float* Wc1  = ws + o; o += 3 * 64;
    float* bf1  = ws + o; o += 64;
    float* Wa2  = ws + o; o += 64 * 128;
    float* Wc2  = ws + o; o += 64 * 128;
    float* bf2  = ws + o; o += 128;
    float* Wa3  = ws + o; o += 192 * 512;
    float* Wc3  = ws + o; o += 192 * 512;
    float* bf3  = ws + o; o += 512;
    int*   idxb = (int*)(ws + o); o += (size_t)MM * KNN;
    int*   dflag = (int*)(ws + o); o += 16;

    // XT / X0 / SQ live in d_out: dead before any final output write.
    float* XT = (float*)d_out;                         // MM*128 floats max
    float* X0 = XT + (size_t)MM * 128;                 // MM*3 floats
    float* SQ = X0 + (size_t)MM * 3;                   // MM floats

    // dtype detect + prep
    detect_dtype_kernel<<<1, 256, 0, stream>>>((const unsigned short*)x, 24576, dflag);
    upcast_kernel<<<(MM * 3 + 255) / 256, 256, 0, stream>>>(x, X0, MM * 3, dflag);
    prep_w_kernel<<<1,   256, 0, stream>>>(W1, b1, Wa1, Wc1, bf1, 3, 64, dflag);
    prep_w_kernel<<<32,  256, 0, stream>>>(W2, b2, Wa2, Wc2, bf2, 64, 128, dflag);
    prep_w_kernel<<<384, 256, 0, stream>>>(W3, b3, Wa3, Wc3, bf3, 192, 512, dflag);

    // Chunked EdgeConv tail: per chunk of width w:
    //   gemm_dual: Cc = X@Wc_slice, Ap = X@Wa_slice + b
    //   gather_fuse: out = act(Ap + gather-max(Cc))
    auto edge_tail = [&](const float* A1, int K1, const float* A2, int K2,
                         const float* Wa, const float* Wc, const float* bfp, int Cout,
                         void* outp, int ldo, int relu, bool final) {
        for (int n0 = 0; n0 < Cout; ) {
            int w = Cout - n0 < CW ? Cout - n0 : CW;
            dim3 g(w / 64, MM / 64);
            gemm_dual<<<g, 256, 0, stream>>>(A1, K1, A2, K2, Wc + n0, Wa + n0,
                                             Cout, bfp + n0, Cc, Ap, w);
            if (final)
                gather_fuse<1><<<MM, w, 0, stream>>>(Cc, Ap, idxb, w, outp, ldo,
                                                     n0, relu, dflag);
            else
                gather_fuse<0><<<MM, w, 0, stream>>>(Cc, Ap, idxb, w, outp, ldo,
                                                     n0, relu, dflag);
            n0 += w;
        }
    };

    // ---- stage 1 (C=3 -> 64)
    sqnorm_kernel<<<MM / 256, 256, 0, stream>>>(X0, SQ, 3);
    transpose_kernel<<<dim3(NN / 32, 1, BB), dim3(32, 8), 0, stream>>>(X0, XT, 3);
    knn_kernel<<<MM / TI, 256, 0, stream>>>(X0, XT, SQ, 3, idxb);
    edge_tail(X0, 3, nullptr, 0, Wa1, Wc1, bf1, 64, (void*)X1, 64, 1, false);

    // ---- stage 2 (C=64 -> 128)
    sqnorm_kernel<<<MM / 256, 256, 0, stream>>>(X1, SQ, 64);
    transpose_kernel<<<dim3(NN / 32, 2, BB), dim3(32, 8), 0, stream>>>(X1, XT, 64);
    knn_kernel<<<MM / TI, 256, 0, stream>>>(X1, XT, SQ, 64, idxb);
    edge_tail(X1, 64, nullptr, 0, Wa2, Wc2, bf2, 128, (void*)X2, 128, 1, false);

    // ---- stage 3 (C=192 = [X1|X2] -> 512, no relu, final out)
    sqnorm_kernel<<<MM / 256, 256, 0, stream>>>(X2, SQ, 128);
    transpose_kernel<<<dim3(NN / 32, 4, BB), dim3(32, 8), 0, stream>>>(X2, XT, 128);
    knn_kernel<<<MM / TI, 256, 0, stream>>>(X2, XT, SQ, 128, idxb);
    edge_tail(X1, 64, X2, 128, Wa3, Wc3, bf3, 512, d_out, 512, 0, true);
}